// Round 6
// baseline (14325.912 us; speedup 1.0000x reference)
//
#include <hip/hip_runtime.h>
#include <cstdint>
#include <cstddef>

#define T_SEQ 4096
#define HSZ   512
#define NGATE 2048   // 4*HSZ
#define DIN   1024
#define NB0   16     // layer-0 blocks per direction
#define HB0   32     // h-elements per layer-0 block (128 gate rows)
#define NB1   32     // layer-1 blocks per direction
#define HB1   16     // h-elements per layer-1 block (64 gate rows)
#define SLOTS 8      // exchange slots (epoch & 7)
#define CST   68     // skewed LDS chunk stride (64 + 4 floats) -> conflict-free b128 chunk reads

typedef unsigned long long u64;
typedef unsigned int u32;

__device__ __forceinline__ u64 exld(const u64* p) {
  return __hip_atomic_load(p, __ATOMIC_RELAXED, __HIP_MEMORY_SCOPE_AGENT);
}
__device__ __forceinline__ void exst(u64* p, u64 v) {
  __hip_atomic_store(p, v, __ATOMIC_RELAXED, __HIP_MEMORY_SCOPE_AGENT);
}
__device__ __forceinline__ int pgld(const u32* p) {
  return (int)__hip_atomic_load(p, __ATOMIC_RELAXED, __HIP_MEMORY_SCOPE_AGENT);
}
__device__ __forceinline__ void pgst(u32* p, u32 v) {
  __hip_atomic_store(p, v, __ATOMIC_RELAXED, __HIP_MEMORY_SCOPE_AGENT);
}

// pipelined poll: 3 loads in flight, check oldest -> detect granularity ~RT/3
__device__ __forceinline__ float poll3(const u64* p, u32 want) {
  u64 a = exld(p), b = exld(p), c = exld(p);
  while ((u32)(a >> 32) != want) { a = b; b = c; c = exld(p); }
  return __uint_as_float((u32)a);
}

__device__ __forceinline__ float fsigmoid(float x) { return 1.f / (1.f + __expf(-x)); }
__device__ __forceinline__ float ftanh(float x) {
  x = fminf(fmaxf(x, -10.f), 10.f);
  const float e = __expf(2.f * x);
  return (e - 1.f) / (e + 1.f);
}
__device__ __forceinline__ float dot4(float4 a, float4 b) {
  return a.x*b.x + a.y*b.y + a.z*b.z + a.w*b.w;
}

// ---------------- init: zero exchange slots (epoch0 == h_0 == 0) + progress flags ----------------
__global__ void init_sync_kernel(u64* ex, u32* prog) {
  const int tid = blockIdx.x * blockDim.x + threadIdx.x;
  const int NEX = 2 * 2 * SLOTS * HSZ;           // ex0 + ex1
  for (int i = tid; i < NEX; i += gridDim.x * blockDim.x) exst(&ex[i], 0ull);
  if (tid < 2 * (NB0 + NB1)) pgst(&prog[tid], 0u);
}

// ---------------- fp32 GEMM with bias: P[t,r] = sum_k X[t,k]*W[r,k] + bi[r] + bh[r] ----------------
__global__ __launch_bounds__(256, 2)
void gemm_bias_kernel(const float* __restrict__ Xf, const float* __restrict__ Xb,
                      const float* __restrict__ Wf, const float* __restrict__ Wb,
                      const float* __restrict__ bif, const float* __restrict__ bhf,
                      const float* __restrict__ bib, const float* __restrict__ bhb,
                      float* __restrict__ Pf, float* __restrict__ Pb, int K)
{
  const int dir = blockIdx.z;
  const float* X  = dir ? Xb  : Xf;
  const float* W  = dir ? Wb  : Wf;
  const float* bi = dir ? bib : bif;
  const float* bh = dir ? bhb : bhf;
  float* P        = dir ? Pb  : Pf;

  const int m0 = blockIdx.x * 128;
  const int n0 = blockIdx.y * 128;
  const int tid = threadIdx.x;
  const int lr = tid >> 1;
  const int lk = (tid & 1) * 8;

  __shared__ float As[16*128];
  __shared__ float Bs[16*128];

  float acc[8][8];
  #pragma unroll
  for (int i = 0; i < 8; ++i)
    #pragma unroll
    for (int j = 0; j < 8; ++j) acc[i][j] = 0.f;

  for (int k0 = 0; k0 < K; k0 += 16) {
    const float4 a0 = *(const float4*)(X + (size_t)(m0+lr)*K + k0 + lk);
    const float4 a1 = *(const float4*)(X + (size_t)(m0+lr)*K + k0 + lk + 4);
    const float4 b0 = *(const float4*)(W + (size_t)(n0+lr)*K + k0 + lk);
    const float4 b1 = *(const float4*)(W + (size_t)(n0+lr)*K + k0 + lk + 4);
    __syncthreads();
    As[(lk+0)*128+lr]=a0.x; As[(lk+1)*128+lr]=a0.y; As[(lk+2)*128+lr]=a0.z; As[(lk+3)*128+lr]=a0.w;
    As[(lk+4)*128+lr]=a1.x; As[(lk+5)*128+lr]=a1.y; As[(lk+6)*128+lr]=a1.z; As[(lk+7)*128+lr]=a1.w;
    Bs[(lk+0)*128+lr]=b0.x; Bs[(lk+1)*128+lr]=b0.y; Bs[(lk+2)*128+lr]=b0.z; Bs[(lk+3)*128+lr]=b0.w;
    Bs[(lk+4)*128+lr]=b1.x; Bs[(lk+5)*128+lr]=b1.y; Bs[(lk+6)*128+lr]=b1.z; Bs[(lk+7)*128+lr]=b1.w;
    __syncthreads();
    #pragma unroll
    for (int kk = 0; kk < 16; ++kk) {
      const float4 A0 = *(const float4*)(As + kk*128 + (tid&15)*8);
      const float4 A1 = *(const float4*)(As + kk*128 + (tid&15)*8 + 4);
      const float4 B0 = *(const float4*)(Bs + kk*128 + (tid>>4)*8);
      const float4 B1 = *(const float4*)(Bs + kk*128 + (tid>>4)*8 + 4);
      const float av[8] = {A0.x,A0.y,A0.z,A0.w,A1.x,A1.y,A1.z,A1.w};
      const float bv[8] = {B0.x,B0.y,B0.z,B0.w,B1.x,B1.y,B1.z,B1.w};
      #pragma unroll
      for (int i = 0; i < 8; ++i)
        #pragma unroll
        for (int j = 0; j < 8; ++j) acc[i][j] += av[i]*bv[j];
    }
  }
  const int tm = m0 + (tid&15)*8;
  const int tn = n0 + (tid>>4)*8;
  #pragma unroll
  for (int i = 0; i < 8; ++i) {
    #pragma unroll
    for (int j = 0; j < 8; ++j) {
      const int n = tn + j;
      P[(size_t)(tm+i)*NGATE + n] = acc[i][j] + bi[n] + bh[n];
    }
  }
}

// ---------------- fused persistent recurrence (single-barrier, in-wave epilogue) ----------------
// blocks [0,32): L0 (16 fwd, 16 bwd)   [32,96): L1 (32 fwd, 32 bwd)
// Per step: pipelined per-thread poll -> double-buffered skewed LDS stage -> ONE barrier ->
// per-lane 2 rows x 64 cols matvec (fat conflict-free ds_read_b128) -> shfl_xor chunk
// reduce -> shfl_down gate gather (all 4 gates of an output in one wave) -> gate math on
// 2 lanes/wave -> immediate per-wave publish (epoch-tagged u64, fire-and-forget).
__global__ __launch_bounds__(512, 2)
void fused_recur_kernel(const float* __restrict__ Whh0_f, const float* __restrict__ Whh0_b,
                        const float* __restrict__ Wih1_f, const float* __restrict__ Whh1_f,
                        const float* __restrict__ bih1_f, const float* __restrict__ bhh1_f,
                        const float* __restrict__ Wih1_b, const float* __restrict__ Whh1_b,
                        const float* __restrict__ bih1_b, const float* __restrict__ bhh1_b,
                        const float* __restrict__ P_f, const float* __restrict__ P_b,
                        u64* ex0, u64* ex1, u32* prog0, u32* prog1,
                        float* __restrict__ out)
{
  const int bx   = blockIdx.x;
  const int tid  = threadIdx.x;
  const int lane = tid & 63;
  const int wv   = tid >> 6;

  __shared__ float xh[2][16*CST];   // double-buffered skewed chunks (L0 uses 8/buf)

  if (bx < 2*NB0) {
    // ================= layer 0 =================
    const int dir = (bx >= NB0) ? 1 : 0;
    const int b   = bx - dir*NB0;
    const float* Whh = dir ? Whh0_b : Whh0_f;
    const float* P   = dir ? P_b    : P_f;
    u64* exS  = ex0 + (size_t)dir*SLOTS*HSZ;
    u32* prS  = prog0 + dir*NB0;
    u32* prL1 = prog1 + dir*NB1;

    const int c  = lane & 7;             // col chunk 0..7 (64 cols each)
    const int p  = lane >> 3;            // row-pair 0..7
    const int g  = p >> 1;               // gate 0..3
    const int j2 = (p & 1) * 2;          // output sub-base 0 or 2
    const int grow0 = g*HSZ + b*HB0 + wv*4 + j2;   // elem0 row; elem1 = grow0+1
    const bool rowner = (c == 0);        // lanes 8p: hold final 2 row-sums

    // weights: 2 rows x 64 cols -> 32 float4 in VGPRs
    float4 w0[16], w1[16];
    {
      const float4* wp0 = (const float4*)(Whh + (size_t)grow0*HSZ + c*64);
      const float4* wp1 = (const float4*)(Whh + (size_t)(grow0+1)*HSZ + c*64);
      #pragma unroll
      for (int m = 0; m < 16; ++m) { w0[m] = wp0[m]; w1[m] = wp1[m]; }
    }

    float2 creg = make_float2(0.f, 0.f);     // lanes 0,8: cell states for 2 outputs
    float2 pv = make_float2(0.f, 0.f);
    if (rowner) pv = *(const float2*)(P + (size_t)(dir ? (T_SEQ-1) : 0)*NGATE + grow0);

    for (int t = 0; t < T_SEQ; ++t) {
      // guard loads issued up-front (overlap with poll), checked after staging
      u32 pr = 0xFFFFFFFFu;
      if (wv == 0 && lane < NB0)      pr = (u32)pgld(&prS[lane]);
      else if (wv == 1 && lane < NB1) pr = (u32)pgld(&prL1[lane]);
      // prefetch next step's P (register-carried)
      float2 pvn = make_float2(0.f, 0.f);
      if (rowner) {
        const int tn = (t+1 < T_SEQ) ? t+1 : t;
        const int te = dir ? (T_SEQ-1-tn) : tn;
        pvn = *(const float2*)(P + (size_t)te*NGATE + grow0);
      }
      // poll own h value (epoch t), stage into skewed chunk layout (stride-1 per wave)
      const float hv = poll3(exS + (size_t)(t & 7)*HSZ + tid, (u32)t);
      xh[t & 1][(tid >> 6)*CST + (tid & 63)] = hv;
      // rare guard spin
      if (wv == 0 && lane < NB0)      { while ((int)pr < t-6) pr = (u32)pgld(&prS[lane]); }
      else if (wv == 1 && lane < NB1) { while ((int)pr < t-6) pr = (u32)pgld(&prL1[lane]); }
      __syncthreads();
      if (tid == 0) pgst(&prS[b], (u32)(t+1));

      // matvec: 2 rows x 64 cols, h chunk read once as b128s
      const float4* h4 = (const float4*)(&xh[t & 1][c*CST]);
      float a00=0.f, a01=0.f, a10=0.f, a11=0.f;
      #pragma unroll
      for (int m = 0; m < 16; m += 2) {
        const float4 h0 = h4[m], h1 = h4[m+1];
        a00 += dot4(w0[m], h0);  a01 += dot4(w0[m+1], h1);
        a10 += dot4(w1[m], h0);  a11 += dot4(w1[m+1], h1);
      }
      float r0 = a00 + a01, r1 = a10 + a11;
      r0 += __shfl_xor(r0, 1); r1 += __shfl_xor(r1, 1);
      r0 += __shfl_xor(r0, 2); r1 += __shfl_xor(r1, 2);
      r0 += __shfl_xor(r0, 4); r1 += __shfl_xor(r1, 4);
      if (rowner) { r0 += pv.x; r1 += pv.y; }
      // gather 4 gates per output into lanes 0 (outputs 4w,4w+1) and 8 (4w+2,4w+3)
      const float f0 = __shfl_down(r0, 16), q0 = __shfl_down(r0, 32), z0 = __shfl_down(r0, 48);
      const float f1 = __shfl_down(r1, 16), q1 = __shfl_down(r1, 32), z1 = __shfl_down(r1, 48);
      if ((lane & 55) == 0) {   // lanes 0 and 8
        const float i_a = fsigmoid(r0), f_a = fsigmoid(f0), g_a = ftanh(q0), o_a = fsigmoid(z0);
        const float i_b = fsigmoid(r1), f_b = fsigmoid(f1), g_b = ftanh(q1), o_b = fsigmoid(z1);
        creg.x = f_a*creg.x + i_a*g_a;
        creg.y = f_b*creg.y + i_b*g_b;
        const float hA = o_a*ftanh(creg.x);
        const float hB = o_b*ftanh(creg.y);
        const int o0 = b*HB0 + wv*4 + j2;      // j2 = 0 (lane0) or 2 (lane8)
        u64* dst = exS + (size_t)((t+1) & 7)*HSZ + o0;
        exst(dst,     ((u64)(u32)(t+1) << 32) | (u64)__float_as_uint(hA));
        exst(dst + 1, ((u64)(u32)(t+1) << 32) | (u64)__float_as_uint(hB));
        if (t == T_SEQ-1) {
          out[dir*HSZ + o0]          = creg.x;   // cell_memories L0
          out[dir*HSZ + o0 + 1]      = creg.y;
          out[2048 + dir*HSZ + o0]   = hA;       // hidden_states L0
          out[2048 + dir*HSZ + o0+1] = hB;
        }
      }
      pv = pvn;
    }
  } else {
    // ================= layer 1 =================
    const int r   = bx - 2*NB0;
    const int dir = (r >= NB1) ? 1 : 0;
    const int b   = r - dir*NB1;
    const float* Wih = dir ? Wih1_b : Wih1_f;
    const float* Whh = dir ? Whh1_b : Whh1_f;
    const float* bi  = dir ? bih1_b : bih1_f;
    const float* bh  = dir ? bhh1_b : bhh1_f;
    u64* exX = ex0 + (size_t)dir*SLOTS*HSZ;
    u64* exS = ex1 + (size_t)dir*SLOTS*HSZ;
    u32* prS = prog1 + dir*NB1;

    const int c = lane & 15;             // col chunk 0..15 (0-7: x via Wih, 8-15: h via Whh)
    const int p = lane >> 4;             // gate 0..3
    const int grow0 = p*HSZ + b*HB1 + wv*2;        // elem0 row; elem1 = +1
    const bool rowner = (c == 0);        // lanes 0,16,32,48

    float4 w0[16], w1[16];
    {
      const float* base0 = (c < 8) ? (Wih + (size_t)grow0*HSZ + c*64)
                                   : (Whh + (size_t)grow0*HSZ + (c-8)*64);
      const float* base1 = (c < 8) ? (Wih + (size_t)(grow0+1)*HSZ + c*64)
                                   : (Whh + (size_t)(grow0+1)*HSZ + (c-8)*64);
      const float4* wp0 = (const float4*)base0;
      const float4* wp1 = (const float4*)base1;
      #pragma unroll
      for (int m = 0; m < 16; ++m) { w0[m] = wp0[m]; w1[m] = wp1[m]; }
    }
    float2 brow = make_float2(0.f, 0.f);
    if (rowner) brow = make_float2(bi[grow0] + bh[grow0], bi[grow0+1] + bh[grow0+1]);

    float2 creg = make_float2(0.f, 0.f);     // lane 0: cell states for outputs 2w, 2w+1
    for (int t = 0; t < T_SEQ; ++t) {
      u32 pr = 0xFFFFFFFFu;
      if (wv == 0 && lane < NB1) pr = (u32)pgld(&prS[lane]);
      // poll x_t (L0 epoch t+1) then own h_t (epoch t, usually already arrived)
      const float xv = poll3(exX + (size_t)((t+1) & 7)*HSZ + tid, (u32)(t+1));
      const float hv = poll3(exS + (size_t)(t & 7)*HSZ + tid,     (u32)t);
      xh[t & 1][(tid >> 6)*CST + (tid & 63)]       = xv;   // chunks 0..7
      xh[t & 1][(8 + (tid >> 6))*CST + (tid & 63)] = hv;   // chunks 8..15
      if (wv == 0 && lane < NB1) { while ((int)pr < t-6) pr = (u32)pgld(&prS[lane]); }
      __syncthreads();
      if (tid == 0) pgst(&prS[b], (u32)(t+1));

      const float4* h4 = (const float4*)(&xh[t & 1][c*CST]);
      float a00=0.f, a01=0.f, a10=0.f, a11=0.f;
      #pragma unroll
      for (int m = 0; m < 16; m += 2) {
        const float4 h0 = h4[m], h1 = h4[m+1];
        a00 += dot4(w0[m], h0);  a01 += dot4(w0[m+1], h1);
        a10 += dot4(w1[m], h0);  a11 += dot4(w1[m+1], h1);
      }
      float r0 = a00 + a01, r1 = a10 + a11;
      r0 += __shfl_xor(r0, 1); r1 += __shfl_xor(r1, 1);
      r0 += __shfl_xor(r0, 2); r1 += __shfl_xor(r1, 2);
      r0 += __shfl_xor(r0, 4); r1 += __shfl_xor(r1, 4);
      r0 += __shfl_xor(r0, 8); r1 += __shfl_xor(r1, 8);
      if (rowner) { r0 += brow.x; r1 += brow.y; }
      const float f0 = __shfl_down(r0, 16), q0 = __shfl_down(r0, 32), z0 = __shfl_down(r0, 48);
      const float f1 = __shfl_down(r1, 16), q1 = __shfl_down(r1, 32), z1 = __shfl_down(r1, 48);
      if (lane == 0) {   // outputs 2w (elem0), 2w+1 (elem1)
        const float i_a = fsigmoid(r0), f_a = fsigmoid(f0), g_a = ftanh(q0), o_a = fsigmoid(z0);
        const float i_b = fsigmoid(r1), f_b = fsigmoid(f1), g_b = ftanh(q1), o_b = fsigmoid(z1);
        creg.x = f_a*creg.x + i_a*g_a;
        creg.y = f_b*creg.y + i_b*g_b;
        const float hA = o_a*ftanh(creg.x);
        const float hB = o_b*ftanh(creg.y);
        const int o0 = b*HB1 + wv*2;
        u64* dst = exS + (size_t)((t+1) & 7)*HSZ + o0;
        exst(dst,     ((u64)(u32)(t+1) << 32) | (u64)__float_as_uint(hA));
        exst(dst + 1, ((u64)(u32)(t+1) << 32) | (u64)__float_as_uint(hB));
        const int trow = dir ? (T_SEQ-1-t) : t;
        *(float2*)(out + 4096 + (size_t)trow*1024 + dir*HSZ + o0) = make_float2(hA, hB);
        if (t == T_SEQ-1) {
          out[1024 + dir*HSZ + o0]          = creg.x;   // cell_memories L1
          out[1024 + dir*HSZ + o0 + 1]      = creg.y;
          out[3072 + dir*HSZ + o0]          = hA;       // hidden_states L1
          out[3072 + dir*HSZ + o0 + 1]      = hB;
        }
      }
    }
  }
}

// ---------------- launch ----------------
extern "C" void kernel_launch(void* const* d_in, const int* in_sizes, int n_in,
                              void* d_out, int out_size, void* d_ws, size_t ws_size,
                              hipStream_t stream)
{
  const float* emb   = (const float*)d_in[0];
  const float* fWih0 = (const float*)d_in[1];
  const float* fWhh0 = (const float*)d_in[2];
  const float* fbih0 = (const float*)d_in[3];
  const float* fbhh0 = (const float*)d_in[4];
  const float* fWih1 = (const float*)d_in[5];
  const float* fWhh1 = (const float*)d_in[6];
  const float* fbih1 = (const float*)d_in[7];
  const float* fbhh1 = (const float*)d_in[8];
  const float* bWih0 = (const float*)d_in[9];
  const float* bWhh0 = (const float*)d_in[10];
  const float* bbih0 = (const float*)d_in[11];
  const float* bbhh0 = (const float*)d_in[12];
  const float* bWih1 = (const float*)d_in[13];
  const float* bWhh1 = (const float*)d_in[14];
  const float* bbih1 = (const float*)d_in[15];
  const float* bbhh1 = (const float*)d_in[16];
  float* out = (float*)d_out;

  // ws: P[2][4096][2048] fp32, ex0/ex1 [2][8][512] u64 each, prog flags
  float* P_f = (float*)d_ws;
  float* P_b = P_f + (size_t)T_SEQ*NGATE;
  u64*   ex0 = (u64*)(P_b + (size_t)T_SEQ*NGATE);
  u64*   ex1 = ex0 + (size_t)2*SLOTS*HSZ;
  u32*   prog0 = (u32*)(ex1 + (size_t)2*SLOTS*HSZ);
  u32*   prog1 = prog0 + 2*NB0;

  init_sync_kernel<<<16, 1024, 0, stream>>>(ex0, prog0);

  gemm_bias_kernel<<<dim3(32,16,2), 256, 0, stream>>>(
      emb, emb, fWih0, bWih0, fbih0, fbhh0, bbih0, bbhh0, P_f, P_b, DIN);

  fused_recur_kernel<<<96, 512, 0, stream>>>(
      fWhh0, bWhh0,
      fWih1, fWhh1, fbih1, fbhh1,
      bWih1, bWhh1, bbih1, bbhh1,
      P_f, P_b, ex0, ex1, prog0, prog1, out);
}